// Round 1
// baseline (59.611 us; speedup 1.0000x reference)
//
#include <hip/hip_runtime.h>

#define BB 8
#define HH 64
#define WW 2048
#define NC 20

// tile: 4 rows x 64 cols per 256-thread block
// depth halo = 4 (9x9 neighborhood), label halo = 2 (5x5 neighborhood)

__global__ __launch_bounds__(256) void knn_refine(
    const float* __restrict__ depth,
    const int*   __restrict__ label,
    const float* __restrict__ wker,
    int*         __restrict__ out)
{
    __shared__ float sD[12][72];
    __shared__ int   sL[8][68];

    const int b  = blockIdx.z;
    const int y0 = blockIdx.y * 4;
    const int x0 = blockIdx.x * 64;
    const int t  = threadIdx.x;

    const float* Db = depth + (size_t)b * (HH * WW);
    const int*   Lb = label + (size_t)b * (HH * WW);

    // ---- stage depth tile (+4 halo). OOB sentinel = -1 (real depth >= 0) ----
    for (int idx = t; idx < 12 * 72; idx += 256) {
        int ry = idx / 72, rx = idx - ry * 72;
        int gy = y0 + ry - 4, gx = x0 + rx - 4;
        float v = -1.0f;
        if (gy >= 0 && gy < HH && gx >= 0 && gx < WW) v = Db[gy * WW + gx];
        sD[ry][rx] = v;
    }
    // ---- stage label tile (+2 halo). OOB pad = 0 (matches unfold zero-pad) ----
    for (int idx = t; idx < 8 * 68; idx += 256) {
        int ry = idx / 68, rx = idx - ry * 68;
        int gy = y0 + ry - 2, gx = x0 + rx - 2;
        int v = 0;
        if (gy >= 0 && gy < HH && gx >= 0 && gx < WW) v = Lb[gy * WW + gx];
        sL[ry][rx] = v;
    }
    __syncthreads();

    const int px = t & 63;
    const int py = t >> 6;

    // ---- 9x9 depth neighborhood -> registers (static indices only) ----
    float nb[81];
#pragma unroll
    for (int dy = 0; dy < 9; ++dy)
#pragma unroll
        for (int dx = 0; dx < 9; ++dx)
            nb[dy * 9 + dx] = sD[py + dy][px + dx];

    // kernel weights: uniform address -> scalar loads
    float wv[25];
#pragma unroll
    for (int j = 0; j < 25; ++j) wv[j] = wker[j];

    float dist[25];
#pragma unroll
    for (int k = 0; k < 25; ++k) dist[k] = 0.0f;

    // dist[k](p) = sum_j w[j] * jump[k, p+j-2]
    //   jump[k,q] = |D[q+k-2] - D[q]|, D OOB -> 0-pad -> jump = D[q]
    //   q OOB in p-space -> conv zero-pad -> no contribution (wj = 0)
#pragma unroll
    for (int j = 0; j < 25; ++j) {
        const int jy = j / 5, jx = j % 5;             // tap offset - 2
        const float Dq = nb[(2 + jy) * 9 + (2 + jx)]; // center(4,4) + (jy-2,jx-2)
        const float wj = (Dq < 0.0f) ? 0.0f : wv[j];  // q out of image: skip term
#pragma unroll
        for (int k = 0; k < 25; ++k) {
            const int ky = k / 5, kx = k % 5;
            const float Dqk = nb[(jy + ky) * 9 + (jx + kx)];
            const float jmp = (Dqk < 0.0f) ? Dq : fabsf(Dqk - Dq);
            dist[k] = fmaf(wj, jmp, dist[k]);
        }
    }

    // ---- stable top-5 smallest (ties -> lower k index, matches lax.top_k) ----
    unsigned used = 0u;
    int labs[5];
#pragma unroll
    for (int r = 0; r < 5; ++r) {
        float best = 3.4e38f;
        int bi = 0;
#pragma unroll
        for (int k = 0; k < 25; ++k) {
            if (!((used >> k) & 1u) && dist[k] < best) { best = dist[k]; bi = k; }
        }
        used |= (1u << bi);
        int lv;
        if (best > 1.0f) {            // cutoff: vote dummy class
            lv = NC;
        } else {
            int ky = bi / 5, kx = bi - ky * 5;
            lv = sL[py + ky][px + kx];   // center(py+2,px+2) + (ky-2,kx-2)
        }
        labs[r] = lv;
    }

    // ---- majority vote over 5 labels; argmax ties -> lowest class index ----
    int bestLab = 0, bestCnt = 0;
#pragma unroll
    for (int i = 0; i < 5; ++i) {
        const int li = labs[i];
        int c = 0;
#pragma unroll
        for (int j = 0; j < 5; ++j) c += (labs[j] == li) ? 1 : 0;
        if (li < NC && (c > bestCnt || (c == bestCnt && li < bestLab))) {
            bestCnt = c;
            bestLab = li;
        }
    }

    out[(size_t)b * (HH * WW) + (size_t)(y0 + py) * WW + (x0 + px)] = bestLab;
}

extern "C" void kernel_launch(void* const* d_in, const int* in_sizes, int n_in,
                              void* d_out, int out_size, void* d_ws, size_t ws_size,
                              hipStream_t stream) {
    const float* depth = (const float*)d_in[0];
    const int*   label = (const int*)d_in[1];
    const float* wker  = (const float*)d_in[2];
    int*         out   = (int*)d_out;

    dim3 grid(WW / 64, HH / 4, BB);
    knn_refine<<<grid, dim3(256), 0, stream>>>(depth, label, wker, out);
}